// Round 8
// baseline (244.152 us; speedup 1.0000x reference)
//
#include <hip/hip_runtime.h>
#include <hip/hip_bf16.h>

#define BB   2048
#define TT   240
#define DD   90
#define MM   (BB*TT)          // 491520
#define KDIM (TT*DD)          // 21600
#define NCLS 40
#define NPAD 48               // k2 N padded to 3 MFMA col-tiles
#define KS2  45               // k2 split-K chunks
#define KST  15               // k-steps (x32) per chunk: 45*15*32 = 21600

typedef __bf16 bf16x8 __attribute__((ext_vector_type(8)));
typedef float  f32x4  __attribute__((ext_vector_type(4)));

#define LOG2E  1.44269504f
#define LOG2E2 2.88539008f

__device__ __forceinline__ bf16x8 cvt8(float4 a, float4 b){
    bf16x8 r;
    r[0]=(__bf16)a.x; r[1]=(__bf16)a.y; r[2]=(__bf16)a.z; r[3]=(__bf16)a.w;
    r[4]=(__bf16)b.x; r[5]=(__bf16)b.y; r[6]=(__bf16)b.z; r[7]=(__bf16)b.w;
    return r;
}

__device__ __forceinline__ unsigned pack_bf16(float a, float b){
    unsigned u0 = (unsigned)__builtin_bit_cast(unsigned short, (__bf16)a);
    unsigned u1 = (unsigned)__builtin_bit_cast(unsigned short, (__bf16)b);
    return u0 | (u1 << 16);
}

// sigm(a)*tanh(b) = (Eb-1) / ((1+ea)*(Eb+1)),  ea=e^-a, Eb=e^{2b}: 4 TRANS total
__device__ __forceinline__ float sig_tanh(float a, float b){
    float ea = exp2f(-LOG2E*a);
    float Eb = exp2f(LOG2E2*b);
    return (Eb - 1.f) * __builtin_amdgcn_rcpf((1.f + ea)*(Eb + 1.f));
}

// ---------------------------------------------------------------------------
// pack1: Wtb[c][k] bf16, c = g*96+dd (gates i,g,o), k padded 90->104.
// Bias folded into K: k=90 holds hi(b_ih+b_hh), k=91 holds lo residual;
// x-side fragment supplies 1.0 at k=90,91. k=92..103 zero.
// ---------------------------------------------------------------------------
__global__ void pack1(const float* __restrict__ Wih,
                      const float* __restrict__ bih,
                      const float* __restrict__ bhh,
                      __bf16* __restrict__ wtb)
{
    int id = blockIdx.x*256 + threadIdx.x;
    if (id >= 288*13) return;
    int c  = id / 13;
    int k8 = id - c*13;
    int g  = c / 96, dd = c - g*96;
    int row = (g==0 ? dd : (g==1 ? 180+dd : 270+dd));
    float bv = 0.f, bhi = 0.f, blo = 0.f;
    if (dd < 90){
        bv  = bih[row] + bhh[row];
        bhi = (float)(__bf16)bv;
        blo = bv - bhi;
    }
    bf16x8 v;
    #pragma unroll
    for (int e = 0; e < 8; ++e){
        int k = k8*8 + e;
        float f = 0.f;
        if (dd < 90){
            if (k < 90)       f = Wih[row*90 + k];
            else if (k == 90) f = bhi;
            else if (k == 91) f = blo;
        }
        v[e] = (__bf16)f;
    }
    *(bf16x8*)(wtb + c*104 + k8*8) = v;
}

// ---------------------------------------------------------------------------
// pack2: hi/lo bf16 split of W_out (compensated bf16). [48][21600] each.
// ---------------------------------------------------------------------------
__global__ void pack2(const float* __restrict__ W2,
                      __bf16* __restrict__ w2hi,
                      __bf16* __restrict__ w2lo)
{
    int id = blockIdx.x*256 + threadIdx.x;
    if (id >= NPAD*2700) return;
    int n  = id / 2700;
    int k8 = id - n*2700;
    bf16x8 vh, vl;
    if (n < NCLS){
        #pragma unroll
        for (int e = 0; e < 8; ++e){
            float f = W2[(size_t)n*KDIM + k8*8 + e];
            __bf16 hb = (__bf16)f;
            vh[e] = hb;
            vl[e] = (__bf16)(f - (float)hb);
        }
    } else {
        #pragma unroll
        for (int e = 0; e < 8; ++e){ vh[e] = (__bf16)0.f; vl[e] = (__bf16)0.f; }
    }
    *(bf16x8*)(w2hi + (size_t)n*KDIM + k8*8) = vh;
    *(bf16x8*)(w2lo + (size_t)n*KDIM + k8*8) = vl;
}

// ---------------------------------------------------------------------------
// k1 v8: TLP-maximized gates GEMM. NO LDS, NO barriers, NO prefetch regs.
// Grid (1024 row-blocks, 3 jj-pairs); block = 256 thr = 4 waves
// (rg = wv>>1 in {0,1}, jp = wv&1 -> jj = by*2+jp in {0..5}).
// Wave tile: 16 rows x 16 dd-cols x 3 gates; W-frags (3g x 3ks bf16x8 =
// 36 VGPR) are loop-invariant, loaded ONCE from global (L2-resident).
// acc[3] = 12 VGPR. 15 tiles of 32 rows per block. Latency hidden by
// occupancy (target 5-6 waves/SIMD, 12 blocks/CU), not by ILP prefetch.
// Activation: sig_tanh fused form, 6 TRANS/h instead of 8.
// C^T orientation (r7-verified): mfma(W,x,acc) -> lane l15 = x-row,
// acc[r] -> dd = jj*16 + kg*4 + r (4 consecutive dd -> 2 dword stores).
// ---------------------------------------------------------------------------
__global__ __launch_bounds__(256, 5)
void k1_gates(const float* __restrict__ x,
              const __bf16* __restrict__ wtb,
              __bf16* __restrict__ h)
{
    const int tid  = threadIdx.x;
    const int lane = tid & 63;
    const int wv   = tid >> 6;      // 0..3
    const int rg   = wv >> 1;       // 0..1
    const int jp   = wv & 1;        // 0..1
    const int jj   = blockIdx.y*2 + jp;   // 0..5
    const int l15  = lane & 15;
    const int kg   = lane >> 4;     // 0..3

    // loop-invariant W fragments: row c = g*96 + jj*16 + l15, k = ks*32+kg*8+e
    bf16x8 wf[3][3];
    #pragma unroll
    for (int g = 0; g < 3; ++g){
        const __bf16* wp = wtb + (g*96 + jj*16 + l15)*104 + kg*8;
        #pragma unroll
        for (int ks = 0; ks < 3; ++ks)
            wf[g][ks] = *(const bf16x8*)(wp + ks*32);
    }

    const size_t rbase = (size_t)blockIdx.x*480 + rg*16 + l15;
    const int dd0 = jj*16 + kg*4;

    for (int t = 0; t < 15; ++t){
        const size_t row = rbase + t*32;
        const float* p = x + row*90;

        bf16x8 af0, af1, af2;
        {
            float4 a = *(const float4*)(p + kg*8);
            float4 b = *(const float4*)(p + kg*8 + 4);
            af0 = cvt8(a, b);
        }
        {
            float4 a = *(const float4*)(p + 32 + kg*8);
            float4 b = *(const float4*)(p + 32 + kg*8 + 4);
            af1 = cvt8(a, b);
        }
        if (kg < 3){
            float4 a = *(const float4*)(p + 64 + kg*8);
            float4 b = *(const float4*)(p + 64 + kg*8 + 4);
            af2 = cvt8(a, b);
        } else {
            // kg=3 covers k=88..95: x88, x89, 1.0 at k=90,91 (bias), zeros
            float2 e2 = *(const float2*)(p + 88);
            bf16x8 z;
            #pragma unroll
            for (int e = 0; e < 8; ++e) z[e] = (__bf16)0.f;
            z[0] = (__bf16)e2.x; z[1] = (__bf16)e2.y;
            z[2] = (__bf16)1.0f; z[3] = (__bf16)1.0f;
            af2 = z;
        }

        f32x4 acc0 = {0.f,0.f,0.f,0.f}, acc1 = acc0, acc2 = acc0;
        acc0 = __builtin_amdgcn_mfma_f32_16x16x32_bf16(wf[0][0], af0, acc0, 0,0,0);
        acc1 = __builtin_amdgcn_mfma_f32_16x16x32_bf16(wf[1][0], af0, acc1, 0,0,0);
        acc2 = __builtin_amdgcn_mfma_f32_16x16x32_bf16(wf[2][0], af0, acc2, 0,0,0);
        acc0 = __builtin_amdgcn_mfma_f32_16x16x32_bf16(wf[0][1], af1, acc0, 0,0,0);
        acc1 = __builtin_amdgcn_mfma_f32_16x16x32_bf16(wf[1][1], af1, acc1, 0,0,0);
        acc2 = __builtin_amdgcn_mfma_f32_16x16x32_bf16(wf[2][1], af1, acc2, 0,0,0);
        acc0 = __builtin_amdgcn_mfma_f32_16x16x32_bf16(wf[0][2], af2, acc0, 0,0,0);
        acc1 = __builtin_amdgcn_mfma_f32_16x16x32_bf16(wf[1][2], af2, acc1, 0,0,0);
        acc2 = __builtin_amdgcn_mfma_f32_16x16x32_bf16(wf[2][2], af2, acc2, 0,0,0);

        // epilogue: 4 h values at consecutive dd = dd0 + r, same x-row (l15)
        float hv[4];
        #pragma unroll
        for (int r = 0; r < 4; ++r){
            float cc = sig_tanh(acc0[r], acc1[r]);   // sigm(i)*tanh(g)
            hv[r]    = sig_tanh(acc2[r], cc);        // sigm(o)*tanh(c)
        }
        __bf16* hp = h + row*90;
        if (dd0 < 90)
            *(unsigned*)(hp + dd0) = pack_bf16(hv[0], hv[1]);
        if (dd0 + 2 < 90)
            *(unsigned*)(hp + dd0 + 2) = pack_bf16(hv[2], hv[3]);
    }
}

// ---------------------------------------------------------------------------
// k2: out GEMM [2048 x 21600] @ [21600 x 48] via MFMA, split-K 45.
// ---------------------------------------------------------------------------
__global__ __launch_bounds__(256)
void k2_out(const __bf16* __restrict__ h,
            const __bf16* __restrict__ w2hi,
            const __bf16* __restrict__ w2lo,
            float* __restrict__ part2)
{
    const int tid  = threadIdx.x;
    const int lane = tid & 63;
    const int wv   = tid >> 6;
    const int l15  = lane & 15;
    const int kg   = lane >> 4;
    const int m0   = (blockIdx.x*4 + wv) * 32;       // 0..2016
    const int chunk= blockIdx.y;                     // 0..44
    const size_t kbase = (size_t)chunk*(KST*32) + 8*kg;

    const __bf16* ha = h    + (size_t)(m0 + l15)*KDIM + kbase;
    const __bf16* hb = ha   + (size_t)16*KDIM;
    const __bf16* h0 = w2hi + (size_t)l15*KDIM + kbase;
    const __bf16* h1 = h0   + (size_t)16*KDIM;
    const __bf16* h2 = h0   + (size_t)32*KDIM;
    const __bf16* l0 = w2lo + (size_t)l15*KDIM + kbase;
    const __bf16* l1 = l0   + (size_t)16*KDIM;
    const __bf16* l2 = l0   + (size_t)32*KDIM;

    f32x4 acc00 = {0.f,0.f,0.f,0.f}, acc01 = acc00, acc02 = acc00;
    f32x4 acc10 = acc00, acc11 = acc00, acc12 = acc00;

    #pragma unroll
    for (int s = 0; s < KST; ++s){
        bf16x8 a0  = *(const bf16x8*)(ha + s*32);
        bf16x8 a1  = *(const bf16x8*)(hb + s*32);
        bf16x8 bh0 = *(const bf16x8*)(h0 + s*32);
        bf16x8 bh1 = *(const bf16x8*)(h1 + s*32);
        bf16x8 bh2 = *(const bf16x8*)(h2 + s*32);
        bf16x8 bl0 = *(const bf16x8*)(l0 + s*32);
        bf16x8 bl1 = *(const bf16x8*)(l1 + s*32);
        bf16x8 bl2 = *(const bf16x8*)(l2 + s*32);
        acc00 = __builtin_amdgcn_mfma_f32_16x16x32_bf16(a0, bh0, acc00, 0,0,0);
        acc01 = __builtin_amdgcn_mfma_f32_16x16x32_bf16(a0, bh1, acc01, 0,0,0);
        acc02 = __builtin_amdgcn_mfma_f32_16x16x32_bf16(a0, bh2, acc02, 0,0,0);
        acc10 = __builtin_amdgcn_mfma_f32_16x16x32_bf16(a1, bh0, acc10, 0,0,0);
        acc11 = __builtin_amdgcn_mfma_f32_16x16x32_bf16(a1, bh1, acc11, 0,0,0);
        acc12 = __builtin_amdgcn_mfma_f32_16x16x32_bf16(a1, bh2, acc12, 0,0,0);
        acc00 = __builtin_amdgcn_mfma_f32_16x16x32_bf16(a0, bl0, acc00, 0,0,0);
        acc01 = __builtin_amdgcn_mfma_f32_16x16x32_bf16(a0, bl1, acc01, 0,0,0);
        acc02 = __builtin_amdgcn_mfma_f32_16x16x32_bf16(a0, bl2, acc02, 0,0,0);
        acc10 = __builtin_amdgcn_mfma_f32_16x16x32_bf16(a1, bl0, acc10, 0,0,0);
        acc11 = __builtin_amdgcn_mfma_f32_16x16x32_bf16(a1, bl1, acc11, 0,0,0);
        acc12 = __builtin_amdgcn_mfma_f32_16x16x32_bf16(a1, bl2, acc12, 0,0,0);
    }

    float* pp = part2 + (size_t)chunk*(BB*NPAD);
    const int rbase = kg*4;
    #pragma unroll
    for (int r = 0; r < 4; ++r){
        size_t row0 = (size_t)(m0 + rbase + r)*NPAD;
        size_t row1 = (size_t)(m0 + 16 + rbase + r)*NPAD;
        pp[row0 +      l15] = acc00[r];
        pp[row0 + 16 + l15] = acc01[r];
        pp[row0 + 32 + l15] = acc02[r];
        pp[row1 +      l15] = acc10[r];
        pp[row1 + 16 + l15] = acc11[r];
        pp[row1 + 32 + l15] = acc12[r];
    }
}

// ---------------------------------------------------------------------------
// k3a: reduce split-K partials + bias -> logits [2048][48]
// ---------------------------------------------------------------------------
__global__ void k3a(const float* __restrict__ part2,
                    const float* __restrict__ bout,
                    float* __restrict__ logits)
{
    int g = blockIdx.x*256 + threadIdx.x;            // < 2048*48
    float s = 0.f;
    for (int c = 0; c < KS2; ++c) s += part2[(size_t)c*(BB*NPAD) + g];
    int n = g % NPAD;
    logits[g] = s + (n < NCLS ? bout[n] : 0.f);
}

// ---------------------------------------------------------------------------
// k3b: softmax over each group of 10
// ---------------------------------------------------------------------------
__global__ void k3b(const float* __restrict__ logits, float* __restrict__ out)
{
    int b = blockIdx.x*256 + threadIdx.x;
    if (b >= BB) return;
    const float* lg = logits + (size_t)b*NPAD;
    #pragma unroll
    for (int g = 0; g < 4; ++g){
        float v[10]; float mx = -1e30f;
        #pragma unroll
        for (int q = 0; q < 10; ++q){ v[q] = lg[g*10+q]; mx = fmaxf(mx, v[q]); }
        float e[10]; float s = 0.f;
        #pragma unroll
        for (int q = 0; q < 10; ++q){ e[q] = __expf(v[q]-mx); s += e[q]; }
        float inv = 1.0f/s;
        #pragma unroll
        for (int q = 0; q < 10; ++q) out[(size_t)b*NCLS + g*10 + q] = e[q]*inv;
    }
}

// ---------------------------------------------------------------------------
extern "C" void kernel_launch(void* const* d_in, const int* in_sizes, int n_in,
                              void* d_out, int out_size, void* d_ws, size_t ws_size,
                              hipStream_t stream)
{
    const float* x    = (const float*)d_in[0];
    const float* Wih  = (const float*)d_in[1];
    // d_in[2] = W_hh unused (zero initial hidden state)
    const float* bih  = (const float*)d_in[3];
    const float* bhh  = (const float*)d_in[4];
    const float* W2   = (const float*)d_in[5];
    const float* bout = (const float*)d_in[6];
    float* out = (float*)d_out;

    char* ws = (char*)d_ws;
    size_t off = 0;
    auto alloc = [&](size_t bytes){ void* p = ws + off; off = (off + bytes + 255) & ~(size_t)255; return p; };
    __bf16* h     = (__bf16*)alloc((size_t)MM*DD*2);           // 88.5 MB
    float*  part2 = (float*) alloc((size_t)KS2*BB*NPAD*4);     // 17.7 MB
    float*  logits= (float*) alloc((size_t)BB*NPAD*4);         // 0.4 MB
    __bf16* wtb   = (__bf16*)alloc(288*104*2);                 // 60 KB
    __bf16* w2hi  = (__bf16*)alloc((size_t)NPAD*KDIM*2);       // 2.1 MB
    __bf16* w2lo  = (__bf16*)alloc((size_t)NPAD*KDIM*2);       // 2.1 MB

    pack1<<<15, 256, 0, stream>>>(Wih, bih, bhh, wtb);
    pack2<<<(NPAD*2700 + 255)/256, 256, 0, stream>>>(W2, w2hi, w2lo);
    k1_gates<<<dim3(1024, 3), 256, 0, stream>>>(x, wtb, h);
    k2_out<<<dim3(16, KS2), 256, 0, stream>>>(h, w2hi, w2lo, part2);
    k3a<<<(BB*NPAD)/256, 256, 0, stream>>>(part2, bout, logits);
    k3b<<<(BB + 255)/256, 256, 0, stream>>>(logits, out);
}

// Round 9
// 138.396 us; speedup vs baseline: 1.7642x; 1.7642x over previous
//
#include <hip/hip_runtime.h>
#include <hip/hip_bf16.h>

#define BB   2048
#define TT   240
#define DD   90
#define MM   (BB*TT)          // 491520
#define KDIM (TT*DD)          // 21600
#define NCLS 40
#define NPAD 48               // k2 N padded to 3 MFMA col-tiles
#define KS2  45               // k2 split-K chunks
#define KST  15               // k-steps (x32) per chunk: 45*15*32 = 21600

typedef __bf16 bf16x8 __attribute__((ext_vector_type(8)));
typedef float  f32x4  __attribute__((ext_vector_type(4)));

#define LOG2E  1.44269504f
#define LOG2E2 2.88539008f

__device__ __forceinline__ bf16x8 cvt8(float4 a, float4 b){
    bf16x8 r;
    r[0]=(__bf16)a.x; r[1]=(__bf16)a.y; r[2]=(__bf16)a.z; r[3]=(__bf16)a.w;
    r[4]=(__bf16)b.x; r[5]=(__bf16)b.y; r[6]=(__bf16)b.z; r[7]=(__bf16)b.w;
    return r;
}

__device__ __forceinline__ unsigned pack_bf16(float a, float b){
    unsigned u0 = (unsigned)__builtin_bit_cast(unsigned short, (__bf16)a);
    unsigned u1 = (unsigned)__builtin_bit_cast(unsigned short, (__bf16)b);
    return u0 | (u1 << 16);
}

// sigm(a)*tanh(b) = (Eb-1) / ((1+ea)*(Eb+1)),  ea=e^-a, Eb=e^{2b}.
// 4 exp + 2 raw v_rcp per h TOTAL (2 calls) -- no IEEE-div fixup sequences
// (r7's sigm/tanh_f used 4 full f32 divides/h: ~40 extra VALU ops each).
__device__ __forceinline__ float sig_tanh(float a, float b){
    float ea = exp2f(-LOG2E*a);
    float Eb = exp2f(LOG2E2*b);
    return (Eb - 1.f) * __builtin_amdgcn_rcpf((1.f + ea)*(Eb + 1.f));
}

// ---------------------------------------------------------------------------
// pack1: Wtb[c][k] bf16, c = g*96+dd (gates i,g,o), k padded 90->104.
// Bias folded into K: k=90 holds hi(b_ih+b_hh), k=91 holds lo residual;
// x-side fragment supplies 1.0 at k=90,91. k=92..103 zero.
// ---------------------------------------------------------------------------
__global__ void pack1(const float* __restrict__ Wih,
                      const float* __restrict__ bih,
                      const float* __restrict__ bhh,
                      __bf16* __restrict__ wtb)
{
    int id = blockIdx.x*256 + threadIdx.x;
    if (id >= 288*13) return;
    int c  = id / 13;
    int k8 = id - c*13;
    int g  = c / 96, dd = c - g*96;
    int row = (g==0 ? dd : (g==1 ? 180+dd : 270+dd));
    float bv = 0.f, bhi = 0.f, blo = 0.f;
    if (dd < 90){
        bv  = bih[row] + bhh[row];
        bhi = (float)(__bf16)bv;
        blo = bv - bhi;
    }
    bf16x8 v;
    #pragma unroll
    for (int e = 0; e < 8; ++e){
        int k = k8*8 + e;
        float f = 0.f;
        if (dd < 90){
            if (k < 90)       f = Wih[row*90 + k];
            else if (k == 90) f = bhi;
            else if (k == 91) f = blo;
        }
        v[e] = (__bf16)f;
    }
    *(bf16x8*)(wtb + c*104 + k8*8) = v;
}

// ---------------------------------------------------------------------------
// pack2: hi/lo bf16 split of W_out (compensated bf16). [48][21600] each.
// ---------------------------------------------------------------------------
__global__ void pack2(const float* __restrict__ W2,
                      __bf16* __restrict__ w2hi,
                      __bf16* __restrict__ w2lo)
{
    int id = blockIdx.x*256 + threadIdx.x;
    if (id >= NPAD*2700) return;
    int n  = id / 2700;
    int k8 = id - n*2700;
    bf16x8 vh, vl;
    if (n < NCLS){
        #pragma unroll
        for (int e = 0; e < 8; ++e){
            float f = W2[(size_t)n*KDIM + k8*8 + e];
            __bf16 hb = (__bf16)f;
            vh[e] = hb;
            vl[e] = (__bf16)(f - (float)hb);
        }
    } else {
        #pragma unroll
        for (int e = 0; e < 8; ++e){ vh[e] = (__bf16)0.f; vl[e] = (__bf16)0.f; }
    }
    *(bf16x8*)(w2hi + (size_t)n*KDIM + k8*8) = vh;
    *(bf16x8*)(w2lo + (size_t)n*KDIM + k8*8) = vl;
}

// ---------------------------------------------------------------------------
// k1: gates GEMM via MFMA, C^T orientation (r7 structure, VERIFIED) +
// division-free activation (r8-verified numerics).
// 512 blocks x 15 tiles of 64 rows; wave = (rg row-group, nh N-half):
// 16 rows x 48 cols x 3 gates. W in LDS once; A-frags direct from global;
// bias via k=90,91; packed dword h-stores (full 64-row x 90-col block
// coverage -> no partial-line write amplification, r8 lesson).
// ---------------------------------------------------------------------------
__global__ __launch_bounds__(512, 2)
void k1_gates(const float* __restrict__ x,
              const __bf16* __restrict__ wtb,
              __bf16* __restrict__ h)
{
    __shared__ __align__(16) __bf16 wt[288*104];   // 59904 B

    const int tid  = threadIdx.x;
    const int lane = tid & 63;
    const int wv   = tid >> 6;      // 0..7
    const int rg   = wv >> 1;       // row group 0..3
    const int nh   = wv & 1;        // N half 0..1
    const int l15  = lane & 15;
    const int kg   = lane >> 4;     // 0..3

    // stage W tile (bf16, packed/padded, bias at k=90,91) -> LDS, once
    {
        const float4* src = (const float4*)wtb;
        float4* dst = (float4*)wt;
        #pragma unroll
        for (int i = 0; i < 8; ++i){
            int idx = tid + i*512;
            if (idx < 3744) dst[idx] = src[idx];
        }
    }
    __syncthreads();

    const int tbase = blockIdx.x * 15;     // 512 blocks * 15 tiles * 64 rows

    // x loads: lane (l15,kg) reads row (rg*16 + l15), k = ks*32 + kg*8 + e
    float4 xr[6];
    float2 xe;
    {
        const float* p = x + ((size_t)tbase*64 + rg*16 + l15)*90;
        #pragma unroll
        for (int ks = 0; ks < 2; ++ks){
            xr[ks*2+0] = *(const float4*)(p + ks*32 + kg*8);
            xr[ks*2+1] = *(const float4*)(p + ks*32 + kg*8 + 4);
        }
        if (kg < 3){
            xr[4] = *(const float4*)(p + 64 + kg*8);
            xr[5] = *(const float4*)(p + 64 + kg*8 + 4);
        } else {
            xe = *(const float2*)(p + 88);
        }
    }

    for (int t = 0; t < 15; ++t){
        // cvt prefetched f32 -> bf16 x-frags (first use waits vmcnt)
        bf16x8 af[3];
        af[0] = cvt8(xr[0], xr[1]);
        af[1] = cvt8(xr[2], xr[3]);
        if (kg < 3){
            af[2] = cvt8(xr[4], xr[5]);
        } else {
            // kg=3 covers k=88..95: x88, x89, then 1.0 at k=90,91 (bias rows)
            bf16x8 z;
            #pragma unroll
            for (int e = 0; e < 8; ++e) z[e] = (__bf16)0.f;
            z[0] = (__bf16)xe.x; z[1] = (__bf16)xe.y;
            z[2] = (__bf16)1.0f; z[3] = (__bf16)1.0f;
            af[2] = z;
        }

        f32x4 acc[3][3];
        #pragma unroll
        for (int g = 0; g < 3; ++g)
            #pragma unroll
            for (int j = 0; j < 3; ++j) acc[g][j] = f32x4{0.f,0.f,0.f,0.f};

        // W-frags: wt row c = g*96 + nh*48 + j*16 + l15, k-offset ks*32 + 8*kg
        // SWAPPED operands: mfma(W, x, acc) -> C row = dd_local, col = m_local
        const __bf16* wbase = wt + (nh*48 + l15)*104 + 8*kg;
        #pragma unroll
        for (int g = 0; g < 3; ++g){
            #pragma unroll
            for (int j = 0; j < 3; ++j){
                const __bf16* wrow = wbase + (g*96 + j*16)*104;
                #pragma unroll
                for (int ks = 0; ks < 3; ++ks){
                    bf16x8 wv8 = *(const bf16x8*)(wrow + ks*32);
                    acc[g][j] = __builtin_amdgcn_mfma_f32_16x16x32_bf16(wv8, af[ks], acc[g][j], 0,0,0);
                }
            }
        }

        // issue next tile's x loads now; epilogue TRANS hides the latency
        if (t < 14){
            const float* p = x + ((size_t)(tbase+t+1)*64 + rg*16 + l15)*90;
            #pragma unroll
            for (int ks = 0; ks < 2; ++ks){
                xr[ks*2+0] = *(const float4*)(p + ks*32 + kg*8);
                xr[ks*2+1] = *(const float4*)(p + ks*32 + kg*8 + 4);
            }
            if (kg < 3){
                xr[4] = *(const float4*)(p + 64 + kg*8);
                xr[5] = *(const float4*)(p + 64 + kg*8 + 4);
            } else {
                xe = *(const float2*)(p + 88);
            }
        }

        // epilogue: lane owns m-row (l15); acc[g][j][r] -> dd = nh*48+j*16+kg*4+r
        // (4 consecutive dd per j: pack pairs -> dword stores)
        const size_t mrow = (size_t)(tbase+t)*64 + rg*16 + l15;
        __bf16* hp = h + mrow*90;
        #pragma unroll
        for (int j = 0; j < 3; ++j){
            int dd0 = nh*48 + j*16 + kg*4;
            float hv[4];
            #pragma unroll
            for (int r = 0; r < 4; ++r){
                float cc = sig_tanh(acc[0][j][r], acc[1][j][r]);  // sigm(i)*tanh(g)
                hv[r]    = sig_tanh(acc[2][j][r], cc);            // sigm(o)*tanh(c)
            }
            if (dd0 < 90)
                *(unsigned*)(hp + dd0) = pack_bf16(hv[0], hv[1]);
            if (dd0 + 2 < 90)
                *(unsigned*)(hp + dd0 + 2) = pack_bf16(hv[2], hv[3]);
        }
    }
}

// ---------------------------------------------------------------------------
// k2: out GEMM [2048 x 21600] @ [21600 x 48] via MFMA, split-K 45.
// ---------------------------------------------------------------------------
__global__ __launch_bounds__(256)
void k2_out(const __bf16* __restrict__ h,
            const __bf16* __restrict__ w2hi,
            const __bf16* __restrict__ w2lo,
            float* __restrict__ part2)
{
    const int tid  = threadIdx.x;
    const int lane = tid & 63;
    const int wv   = tid >> 6;
    const int l15  = lane & 15;
    const int kg   = lane >> 4;
    const int m0   = (blockIdx.x*4 + wv) * 32;       // 0..2016
    const int chunk= blockIdx.y;                     // 0..44
    const size_t kbase = (size_t)chunk*(KST*32) + 8*kg;

    const __bf16* ha = h    + (size_t)(m0 + l15)*KDIM + kbase;
    const __bf16* hb = ha   + (size_t)16*KDIM;
    const __bf16* h0 = w2hi + (size_t)l15*KDIM + kbase;
    const __bf16* h1 = h0   + (size_t)16*KDIM;
    const __bf16* h2 = h0   + (size_t)32*KDIM;
    const __bf16* l0 = w2lo + (size_t)l15*KDIM + kbase;
    const __bf16* l1 = l0   + (size_t)16*KDIM;
    const __bf16* l2 = l0   + (size_t)32*KDIM;

    f32x4 acc00 = {0.f,0.f,0.f,0.f}, acc01 = acc00, acc02 = acc00;
    f32x4 acc10 = acc00, acc11 = acc00, acc12 = acc00;

    #pragma unroll
    for (int s = 0; s < KST; ++s){
        bf16x8 a0  = *(const bf16x8*)(ha + s*32);
        bf16x8 a1  = *(const bf16x8*)(hb + s*32);
        bf16x8 bh0 = *(const bf16x8*)(h0 + s*32);
        bf16x8 bh1 = *(const bf16x8*)(h1 + s*32);
        bf16x8 bh2 = *(const bf16x8*)(h2 + s*32);
        bf16x8 bl0 = *(const bf16x8*)(l0 + s*32);
        bf16x8 bl1 = *(const bf16x8*)(l1 + s*32);
        bf16x8 bl2 = *(const bf16x8*)(l2 + s*32);
        acc00 = __builtin_amdgcn_mfma_f32_16x16x32_bf16(a0, bh0, acc00, 0,0,0);
        acc01 = __builtin_amdgcn_mfma_f32_16x16x32_bf16(a0, bh1, acc01, 0,0,0);
        acc02 = __builtin_amdgcn_mfma_f32_16x16x32_bf16(a0, bh2, acc02, 0,0,0);
        acc10 = __builtin_amdgcn_mfma_f32_16x16x32_bf16(a1, bh0, acc10, 0,0,0);
        acc11 = __builtin_amdgcn_mfma_f32_16x16x32_bf16(a1, bh1, acc11, 0,0,0);
        acc12 = __builtin_amdgcn_mfma_f32_16x16x32_bf16(a1, bh2, acc12, 0,0,0);
        acc00 = __builtin_amdgcn_mfma_f32_16x16x32_bf16(a0, bl0, acc00, 0,0,0);
        acc01 = __builtin_amdgcn_mfma_f32_16x16x32_bf16(a0, bl1, acc01, 0,0,0);
        acc02 = __builtin_amdgcn_mfma_f32_16x16x32_bf16(a0, bl2, acc02, 0,0,0);
        acc10 = __builtin_amdgcn_mfma_f32_16x16x32_bf16(a1, bl0, acc10, 0,0,0);
        acc11 = __builtin_amdgcn_mfma_f32_16x16x32_bf16(a1, bl1, acc11, 0,0,0);
        acc12 = __builtin_amdgcn_mfma_f32_16x16x32_bf16(a1, bl2, acc12, 0,0,0);
    }

    float* pp = part2 + (size_t)chunk*(BB*NPAD);
    const int rbase = kg*4;
    #pragma unroll
    for (int r = 0; r < 4; ++r){
        size_t row0 = (size_t)(m0 + rbase + r)*NPAD;
        size_t row1 = (size_t)(m0 + 16 + rbase + r)*NPAD;
        pp[row0 +      l15] = acc00[r];
        pp[row0 + 16 + l15] = acc01[r];
        pp[row0 + 32 + l15] = acc02[r];
        pp[row1 +      l15] = acc10[r];
        pp[row1 + 16 + l15] = acc11[r];
        pp[row1 + 32 + l15] = acc12[r];
    }
}

// ---------------------------------------------------------------------------
// k3a: reduce split-K partials + bias -> logits [2048][48]
// ---------------------------------------------------------------------------
__global__ void k3a(const float* __restrict__ part2,
                    const float* __restrict__ bout,
                    float* __restrict__ logits)
{
    int g = blockIdx.x*256 + threadIdx.x;            // < 2048*48
    float s = 0.f;
    for (int c = 0; c < KS2; ++c) s += part2[(size_t)c*(BB*NPAD) + g];
    int n = g % NPAD;
    logits[g] = s + (n < NCLS ? bout[n] : 0.f);
}

// ---------------------------------------------------------------------------
// k3b: softmax over each group of 10
// ---------------------------------------------------------------------------
__global__ void k3b(const float* __restrict__ logits, float* __restrict__ out)
{
    int b = blockIdx.x*256 + threadIdx.x;
    if (b >= BB) return;
    const float* lg = logits + (size_t)b*NPAD;
    #pragma unroll
    for (int g = 0; g < 4; ++g){
        float v[10]; float mx = -1e30f;
        #pragma unroll
        for (int q = 0; q < 10; ++q){ v[q] = lg[g*10+q]; mx = fmaxf(mx, v[q]); }
        float e[10]; float s = 0.f;
        #pragma unroll
        for (int q = 0; q < 10; ++q){ e[q] = __expf(v[q]-mx); s += e[q]; }
        float inv = 1.0f/s;
        #pragma unroll
        for (int q = 0; q < 10; ++q) out[(size_t)b*NCLS + g*10 + q] = e[q]*inv;
    }
}

// ---------------------------------------------------------------------------
extern "C" void kernel_launch(void* const* d_in, const int* in_sizes, int n_in,
                              void* d_out, int out_size, void* d_ws, size_t ws_size,
                              hipStream_t stream)
{
    const float* x    = (const float*)d_in[0];
    const float* Wih  = (const float*)d_in[1];
    // d_in[2] = W_hh unused (zero initial hidden state)
    const float* bih  = (const float*)d_in[3];
    const float* bhh  = (const float*)d_in[4];
    const float* W2   = (const float*)d_in[5];
    const float* bout = (const float*)d_in[6];
    float* out = (float*)d_out;

    char* ws = (char*)d_ws;
    size_t off = 0;
    auto alloc = [&](size_t bytes){ void* p = ws + off; off = (off + bytes + 255) & ~(size_t)255; return p; };
    __bf16* h     = (__bf16*)alloc((size_t)MM*DD*2);           // 88.5 MB
    float*  part2 = (float*) alloc((size_t)KS2*BB*NPAD*4);     // 17.7 MB
    float*  logits= (float*) alloc((size_t)BB*NPAD*4);         // 0.4 MB
    __bf16* wtb   = (__bf16*)alloc(288*104*2);                 // 60 KB
    __bf16* w2hi  = (__bf16*)alloc((size_t)NPAD*KDIM*2);       // 2.1 MB
    __bf16* w2lo  = (__bf16*)alloc((size_t)NPAD*KDIM*2);       // 2.1 MB

    pack1<<<15, 256, 0, stream>>>(Wih, bih, bhh, wtb);
    pack2<<<(NPAD*2700 + 255)/256, 256, 0, stream>>>(W2, w2hi, w2lo);
    k1_gates<<<512, 512, 0, stream>>>(x, wtb, h);
    k2_out<<<dim3(16, KS2), 256, 0, stream>>>(h, w2hi, w2lo, part2);
    k3a<<<(BB*NPAD)/256, 256, 0, stream>>>(part2, bout, logits);
    k3b<<<(BB + 255)/256, 256, 0, stream>>>(logits, out);
}